// Round 2
// baseline (373.378 us; speedup 1.0000x reference)
//
#include <hip/hip_runtime.h>

typedef unsigned short u16;
typedef unsigned int u32;
typedef __bf16 bf16x8 __attribute__((ext_vector_type(8)));
typedef float f32x4 __attribute__((ext_vector_type(4)));
typedef unsigned short u16x4 __attribute__((ext_vector_type(4)));
typedef unsigned short u16x8 __attribute__((ext_vector_type(8)));
typedef unsigned int u32x4 __attribute__((ext_vector_type(4)));

#define BB 2
#define SS 2048
#define EE 1024
#define HH 16
#define DD 64

static __device__ inline u16 f2bf(float f) {
    union { float f; unsigned int u; } v; v.f = f;
    unsigned int u = v.u;
    unsigned int r = (u + 0x7FFFu + ((u >> 16) & 1u)) >> 16;  // RNE
    return (u16)r;
}

static __device__ inline u32 cvt_pk_bf16(float lo, float hi) {
    u32 r;
    asm volatile("v_cvt_pk_bf16_f32 %0, %1, %2" : "=v"(r) : "v"(lo), "v"(hi));
    return r;
}

// ---------------- K0a: transpose Wq/Wk/Wv [H,E,D] f32 -> WT [3*1024][1024] bf16 ----------------
__global__ __launch_bounds__(256) void transpose_w_kernel(
    const float* __restrict__ Wq, const float* __restrict__ Wk, const float* __restrict__ Wv,
    u16* __restrict__ WT)
{
    const int z = blockIdx.z;
    const int h = blockIdx.y;
    const int e0 = blockIdx.x * 64;
    const float* W = (z == 0) ? Wq : (z == 1) ? Wk : Wv;
    __shared__ float t_lds[64][68];
    const int tid = threadIdx.x;
#pragma unroll
    for (int it = 0; it < 4; ++it) {
        int s = tid + it * 256;
        int i = s >> 4, d4 = (s & 15) * 4;
        const float4 v = *reinterpret_cast<const float4*>(&W[((size_t)h * EE + e0 + i) * DD + d4]);
        t_lds[i][d4 + 0] = v.x; t_lds[i][d4 + 1] = v.y;
        t_lds[i][d4 + 2] = v.z; t_lds[i][d4 + 3] = v.w;
    }
    __syncthreads();
#pragma unroll
    for (int it = 0; it < 4; ++it) {
        int s = tid + it * 256;
        int d = s >> 4, i4 = (s & 15) * 4;
        u16x4 o;
        o[0] = f2bf(t_lds[i4 + 0][d]); o[1] = f2bf(t_lds[i4 + 1][d]);
        o[2] = f2bf(t_lds[i4 + 2][d]); o[3] = f2bf(t_lds[i4 + 3][d]);
        *reinterpret_cast<u16x4*>(&WT[((size_t)z * 1024 + h * 64 + d) * EE + e0 + i4]) = o;
    }
}

// ---------------- K0b: W2T[e][h*D+d] = sum_o Wo[h,d,o]*Wf[h*O+o,e]; b2 ----------------
__global__ __launch_bounds__(256) void build_w2t_kernel(
    const float* __restrict__ Wo, const float* __restrict__ bo,
    const float* __restrict__ Wf, const float* __restrict__ bfin,
    u16* __restrict__ W2T, float* __restrict__ b2)
{
    const int h = blockIdx.y;
    const int e0 = blockIdx.x * 64;
    __shared__ float wo_lds[64][65];  // [d][o]
    __shared__ float wf_lds[64][65];  // [o][i]
    const int tid = threadIdx.x;
#pragma unroll
    for (int it = 0; it < 4; ++it) {
        int s = tid + it * 256;
        int r = s >> 4, c4 = (s & 15) * 4;
        const float4 a = *reinterpret_cast<const float4*>(&Wo[((size_t)h * 64 + r) * 64 + c4]);
        wo_lds[r][c4 + 0] = a.x; wo_lds[r][c4 + 1] = a.y; wo_lds[r][c4 + 2] = a.z; wo_lds[r][c4 + 3] = a.w;
        const float4 b = *reinterpret_cast<const float4*>(&Wf[((size_t)(h * 64 + r)) * EE + e0 + c4]);
        wf_lds[r][c4 + 0] = b.x; wf_lds[r][c4 + 1] = b.y; wf_lds[r][c4 + 2] = b.z; wf_lds[r][c4 + 3] = b.w;
    }
    __syncthreads();
    const int d = tid & 63;
    const int i0 = (tid >> 6) * 16;
#pragma unroll
    for (int ii = 0; ii < 16; ++ii) {
        int i = i0 + ii;
        float acc = 0.f;
#pragma unroll 8
        for (int o = 0; o < 64; ++o) acc += wo_lds[d][o] * wf_lds[o][i];
        W2T[((size_t)(e0 + i)) * 1024 + h * 64 + d] = f2bf(acc);
    }
    if (tid < 64) {
        int i = tid;
        float acc = 0.f;
        for (int o = 0; o < 64; ++o) acc += bo[h * 64 + o] * wf_lds[o][i];
        if (h == 0) acc += bfin[e0 + i];
        atomicAdd(&b2[e0 + i], acc);
    }
}

// ---------------- K0c: kbias[b][t] = kmask ? 0 : -2e30 ----------------
__global__ __launch_bounds__(256) void kbias_kernel(const float* __restrict__ km, float* __restrict__ kb)
{
    int i = blockIdx.x * 256 + threadIdx.x;
    if (i < BB * SS) kb[i] = (km[i] != 0.f) ? 0.f : -2e30f;
}

// ---------------- K1: QKV projection GEMM ----------------
__global__ __launch_bounds__(256) void gemm_qkv_kernel(
    const float* __restrict__ query, const float* __restrict__ key, const float* __restrict__ value,
    const u16* __restrict__ WT,
    const float* __restrict__ bq, const float* __restrict__ bk, const float* __restrict__ bv,
    u16* __restrict__ qbf, u16* __restrict__ kbf, u16* __restrict__ vbf)
{
    const int z = blockIdx.z;
    const float* A   = (z == 0) ? query : (z == 1) ? key : value;
    const float* bia = (z == 0) ? bq    : (z == 1) ? bk  : bv;
    u16* outp        = (z == 0) ? qbf   : (z == 1) ? kbf : vbf;
    const u16* BT = WT + (size_t)z * 1024 * 1024;

    const int m0 = blockIdx.y * 128;
    const int n0 = blockIdx.x * 128;

    __shared__ u16 a_lds[128][72];
    __shared__ u16 b_lds[128][72];

    const int tid = threadIdx.x;
    const int lane = tid & 63;
    const int w = tid >> 6;
    const int wm = w >> 1, wn = w & 1;
    const int lrow = lane & 15;
    const int lgrp = lane >> 4;

    f32x4 acc[4][4] = {};

    for (int k0 = 0; k0 < 1024; k0 += 64) {
#pragma unroll
        for (int it = 0; it < 8; ++it) {
            int s = tid + it * 256;
            int row = s >> 4, c4 = (s & 15) * 4;
            const float4 v = *reinterpret_cast<const float4*>(&A[(size_t)(m0 + row) * 1024 + k0 + c4]);
            u16x4 o;
            o[0] = f2bf(v.x); o[1] = f2bf(v.y); o[2] = f2bf(v.z); o[3] = f2bf(v.w);
            *reinterpret_cast<u16x4*>(&a_lds[row][c4]) = o;
        }
#pragma unroll
        for (int it = 0; it < 4; ++it) {
            int s = tid + it * 256;
            int row = s >> 3, c8 = (s & 7) * 8;
            *reinterpret_cast<u16x8*>(&b_lds[row][c8]) =
                *reinterpret_cast<const u16x8*>(&BT[(size_t)(n0 + row) * 1024 + k0 + c8]);
        }
        __syncthreads();

#pragma unroll
        for (int kk = 0; kk < 2; ++kk) {
            bf16x8 af[4], bfr[4];
#pragma unroll
            for (int i = 0; i < 4; ++i)
                af[i] = *reinterpret_cast<const bf16x8*>(&a_lds[wm * 64 + i * 16 + lrow][kk * 32 + lgrp * 8]);
#pragma unroll
            for (int j = 0; j < 4; ++j)
                bfr[j] = *reinterpret_cast<const bf16x8*>(&b_lds[wn * 64 + j * 16 + lrow][kk * 32 + lgrp * 8]);
#pragma unroll
            for (int i = 0; i < 4; ++i)
#pragma unroll
                for (int j = 0; j < 4; ++j)
                    acc[i][j] = __builtin_amdgcn_mfma_f32_16x16x32_bf16(af[i], bfr[j], acc[i][j], 0, 0, 0);
        }
        __syncthreads();
    }

#pragma unroll
    for (int i = 0; i < 4; ++i) {
#pragma unroll
        for (int j = 0; j < 4; ++j) {
            int n = n0 + wn * 64 + j * 16 + lrow;
            int h = n >> 6, d = n & 63;
            float bb = bia[n];
#pragma unroll
            for (int r = 0; r < 4; ++r) {
                int m = m0 + wm * 64 + i * 16 + lgrp * 4 + r;
                int b = m >> 11, srow = m & 2047;
                outp[((size_t)(b * HH + h) * SS + srow) * DD + d] = f2bf(acc[i][j][r] + bb);
            }
        }
    }
}

// ---------------- K1b: transpose V [B,H,S,D] -> [B,H,D,S] (bf16) ----------------
__global__ __launch_bounds__(256) void transpose_v_kernel(
    const u16* __restrict__ vbf, u16* __restrict__ vtg)
{
    const int s0 = blockIdx.x * 64;
    const int bh = blockIdx.y;
    __shared__ u16 t_lds[64][72];
    const int tid = threadIdx.x;
#pragma unroll
    for (int rr = 0; rr < 2; ++rr) {
        int idx = tid + rr * 256;
        int row = idx >> 3, c8 = (idx & 7) * 8;
        *reinterpret_cast<u16x8*>(&t_lds[row][c8]) =
            *reinterpret_cast<const u16x8*>(&vbf[((size_t)bh * SS + s0 + row) * DD + c8]);
    }
    __syncthreads();
#pragma unroll
    for (int rr = 0; rr < 2; ++rr) {
        int idx = tid + rr * 256;
        int d = idx >> 3, tt = (idx & 7) * 8;
        u16x8 o;
#pragma unroll
        for (int j = 0; j < 8; ++j) o[j] = t_lds[tt + j][d];
        *reinterpret_cast<u16x8*>(&vtg[((size_t)bh * DD + d) * SS + s0 + tt]) = o;
    }
}

// ---------------- K2: flash attention, swapped QK^T, no LDS, direct L2 reads ----------------
__global__ __launch_bounds__(256, 4) void attn_kernel(
    const u16* __restrict__ qbf, const u16* __restrict__ kbf, const u16* __restrict__ vtg,
    const float* __restrict__ kbias, const float* __restrict__ qmask,
    u16* __restrict__ att)
{
    // XCD/CU-aware swizzle: same-CU blocks share (b,h) so K/V stream is L1/L2-resident
    const int id = blockIdx.x;
    const int bh = (id & 7) * 4 + ((id >> 3) & 3);
    const int qt = (id >> 3) >> 2;
    const int b = bh >> 4, h = bh & 15;

    const int tid = threadIdx.x;
    const int w = tid >> 6;
    const int lane = tid & 63;
    const int lrow = lane & 15, lgrp = lane >> 4;
    const int q0 = qt * 64 + w * 16;

    const size_t bhoff = (size_t)bh * SS * DD;

    // Q as MFMA B-operand: col=q=lane&15, k=d
    bf16x8 aq[2];
#pragma unroll
    for (int kk = 0; kk < 2; ++kk)
        aq[kk] = *reinterpret_cast<const bf16x8*>(&qbf[bhoff + (size_t)(q0 + lrow) * DD + kk * 32 + lgrp * 8]);

    // per-lane base pointers (advanced each tile)
    const u16* kp = kbf + bhoff + (size_t)lrow * DD + lgrp * 8;
    const u16* vp0 = vtg + ((size_t)bh * DD + 0 * 16 + lrow) * SS + lgrp * 8;
    const u16* vp1 = vtg + ((size_t)bh * DD + 1 * 16 + lrow) * SS + lgrp * 8;
    const u16* vp2 = vtg + ((size_t)bh * DD + 2 * 16 + lrow) * SS + lgrp * 8;
    const u16* vp3 = vtg + ((size_t)bh * DD + 3 * 16 + lrow) * SS + lgrp * 8;
    const float* kbp = kbias + (size_t)b * SS + lgrp * 4;

    f32x4 acc[4] = {};   // O[q'=lgrp*4+r][d=nf*16+lrow]
    float m_run = -1e30f, l_run = 0.f;
    const float sscale = 0.125f * 1.44269504089f;  // 1/sqrt(64) * log2(e)

    for (int ti = 0; ti < 32; ++ti) {
        // K A-frags: row t = nt*16+lrow, k = d
        bf16x8 kf[4][2];
#pragma unroll
        for (int nt = 0; nt < 4; ++nt) {
            kf[nt][0] = *reinterpret_cast<const bf16x8*>(kp + nt * 1024);
            kf[nt][1] = *reinterpret_cast<const bf16x8*>(kp + nt * 1024 + 32);
        }
        float4 kb4[4];
#pragma unroll
        for (int nt = 0; nt < 4; ++nt)
            kb4[nt] = *reinterpret_cast<const float4*>(kbp + nt * 16);

        // swapped QK^T: C[t][q], lane holds q=lane&15, t = nt*16 + lgrp*4 + reg
        f32x4 sc4[4];
#pragma unroll
        for (int nt = 0; nt < 4; ++nt) {
            f32x4 s = {};
            s = __builtin_amdgcn_mfma_f32_16x16x32_bf16(kf[nt][0], aq[0], s, 0, 0, 0);
            s = __builtin_amdgcn_mfma_f32_16x16x32_bf16(kf[nt][1], aq[1], s, 0, 0, 0);
            sc4[nt] = s;
        }

        // V B-frags issued now (hidden under softmax VALU)
        bf16x8 vf[4][2];
#pragma unroll
        for (int kk2 = 0; kk2 < 2; ++kk2) {
            vf[0][kk2] = *reinterpret_cast<const bf16x8*>(vp0 + kk2 * 32);
            vf[1][kk2] = *reinterpret_cast<const bf16x8*>(vp1 + kk2 * 32);
            vf[2][kk2] = *reinterpret_cast<const bf16x8*>(vp2 + kk2 * 32);
            vf[3][kk2] = *reinterpret_cast<const bf16x8*>(vp3 + kk2 * 32);
        }

        // scale + additive mask bias (log2 domain)
        float p[4][4];
        float vmax = -3.0e38f;
        float kbv[4][4];
#pragma unroll
        for (int nt = 0; nt < 4; ++nt) {
            kbv[nt][0] = kb4[nt].x; kbv[nt][1] = kb4[nt].y;
            kbv[nt][2] = kb4[nt].z; kbv[nt][3] = kb4[nt].w;
        }
#pragma unroll
        for (int nt = 0; nt < 4; ++nt)
#pragma unroll
            for (int r = 0; r < 4; ++r) {
                float x = sc4[nt][r] * sscale + kbv[nt][r];
                p[nt][r] = x;
                vmax = fmaxf(vmax, x);
            }
        vmax = fmaxf(vmax, __shfl_xor(vmax, 16));
        vmax = fmaxf(vmax, __shfl_xor(vmax, 32));

        // defer-max (T13): only rescale when max grew by >8 (log2)
        if (!__all((vmax - m_run) <= 8.0f)) {
            float mnew = fmaxf(m_run, vmax);
            float alpha = exp2f(m_run - mnew);
            m_run = mnew;
            l_run *= alpha;
#pragma unroll
            for (int r = 0; r < 4; ++r) {
                float ar = __shfl(alpha, lgrp * 4 + r);
#pragma unroll
                for (int nf = 0; nf < 4; ++nf) acc[nf][r] *= ar;
            }
        }

        float psum = 0.f;
#pragma unroll
        for (int nt = 0; nt < 4; ++nt)
#pragma unroll
            for (int r = 0; r < 4; ++r) {
                float e = exp2f(p[nt][r] - m_run);
                p[nt][r] = e;
                psum += e;
            }
        l_run += psum;

        // pack P to bf16 pairs: hh[nt][u] = pack(P[t],P[t+1]), t = nt*16+lgrp*4+2u
        u32 hh[4][2];
#pragma unroll
        for (int nt = 0; nt < 4; ++nt) {
            hh[nt][0] = cvt_pk_bf16(p[nt][0], p[nt][1]);
            hh[nt][1] = cvt_pk_bf16(p[nt][2], p[nt][3]);
        }

        // exchange into PV A-frag layout: lane needs t = kk2*32 + lgrp*8 + j
        const int src_lo = lrow + ((lgrp & 1) << 5);
        const int src_hi = src_lo + 16;
        const bool hiSel = (lgrp >> 1) & 1;
#pragma unroll
        for (int kk2 = 0; kk2 < 2; ++kk2) {
            u32 w0l = __shfl(hh[2 * kk2][0], src_lo);
            u32 w0h = __shfl(hh[2 * kk2 + 1][0], src_lo);
            u32 w1l = __shfl(hh[2 * kk2][1], src_lo);
            u32 w1h = __shfl(hh[2 * kk2 + 1][1], src_lo);
            u32 w2l = __shfl(hh[2 * kk2][0], src_hi);
            u32 w2h = __shfl(hh[2 * kk2 + 1][0], src_hi);
            u32 w3l = __shfl(hh[2 * kk2][1], src_hi);
            u32 w3h = __shfl(hh[2 * kk2 + 1][1], src_hi);
            u32x4 a4;
            a4[0] = hiSel ? w0h : w0l;
            a4[1] = hiSel ? w1h : w1l;
            a4[2] = hiSel ? w2h : w2l;
            a4[3] = hiSel ? w3h : w3l;
            bf16x8 pa = __builtin_bit_cast(bf16x8, a4);
#pragma unroll
            for (int nf = 0; nf < 4; ++nf)
                acc[nf] = __builtin_amdgcn_mfma_f32_16x16x32_bf16(pa, vf[nf][kk2], acc[nf], 0, 0, 0);
        }

        kp += 64 * DD;
        vp0 += 64; vp1 += 64; vp2 += 64; vp3 += 64;
        kbp += 64;
    }

    // epilogue: combine l across the 4 lane-groups, normalize, store
    float l1 = l_run + __shfl_xor(l_run, 16);
    l1 += __shfl_xor(l1, 32);
#pragma unroll
    for (int r = 0; r < 4; ++r) {
        int qq = lgrp * 4 + r;
        float lq = __shfl(l1, qq);
        float qm = qmask[(size_t)b * SS + q0 + qq];
        float inv = (lq > 0.f && qm != 0.f) ? 1.f / lq : 0.f;
#pragma unroll
        for (int nf = 0; nf < 4; ++nf)
            att[((size_t)b * SS + q0 + qq) * 1024 + h * 64 + nf * 16 + lrow] = f2bf(acc[nf][r] * inv);
    }
}

// ---------------- K3: final GEMM: att[4096,1024] bf16 x W2T -> out f32 + b2 ----------------
__global__ __launch_bounds__(256) void gemm_final_kernel(
    const u16* __restrict__ A, const u16* __restrict__ BT,
    const float* __restrict__ b2, float* __restrict__ out)
{
    const int m0 = blockIdx.y * 128;
    const int n0 = blockIdx.x * 128;

    __shared__ u16 a_lds[128][72];
    __shared__ u16 b_lds[128][72];

    const int tid = threadIdx.x;
    const int lane = tid & 63;
    const int w = tid >> 6;
    const int wm = w >> 1, wn = w & 1;
    const int lrow = lane & 15;
    const int lgrp = lane >> 4;

    f32x4 acc[4][4] = {};

    for (int k0 = 0; k0 < 1024; k0 += 64) {
#pragma unroll
        for (int it = 0; it < 4; ++it) {
            int s = tid + it * 256;
            int row = s >> 3, c8 = (s & 7) * 8;
            *reinterpret_cast<u16x8*>(&a_lds[row][c8]) =
                *reinterpret_cast<const u16x8*>(&A[(size_t)(m0 + row) * 1024 + k0 + c8]);
        }
#pragma unroll
        for (int it = 0; it < 4; ++it) {
            int s = tid + it * 256;
            int row = s >> 3, c8 = (s & 7) * 8;
            *reinterpret_cast<u16x8*>(&b_lds[row][c8]) =
                *reinterpret_cast<const u16x8*>(&BT[(size_t)(n0 + row) * 1024 + k0 + c8]);
        }
        __syncthreads();

#pragma unroll
        for (int kk = 0; kk < 2; ++kk) {
            bf16x8 af[4], bfr[4];
#pragma unroll
            for (int i = 0; i < 4; ++i)
                af[i] = *reinterpret_cast<const bf16x8*>(&a_lds[wm * 64 + i * 16 + lrow][kk * 32 + lgrp * 8]);
#pragma unroll
            for (int j = 0; j < 4; ++j)
                bfr[j] = *reinterpret_cast<const bf16x8*>(&b_lds[wn * 64 + j * 16 + lrow][kk * 32 + lgrp * 8]);
#pragma unroll
            for (int i = 0; i < 4; ++i)
#pragma unroll
                for (int j = 0; j < 4; ++j)
                    acc[i][j] = __builtin_amdgcn_mfma_f32_16x16x32_bf16(af[i], bfr[j], acc[i][j], 0, 0, 0);
        }
        __syncthreads();
    }

#pragma unroll
    for (int i = 0; i < 4; ++i) {
#pragma unroll
        for (int j = 0; j < 4; ++j) {
            int n = n0 + wn * 64 + j * 16 + lrow;
            float bb = b2[n];
#pragma unroll
            for (int r = 0; r < 4; ++r) {
                int m = m0 + wm * 64 + i * 16 + lgrp * 4 + r;
                out[(size_t)m * 1024 + n] = acc[i][j][r] + bb;
            }
        }
    }
}

extern "C" void kernel_launch(void* const* d_in, const int* in_sizes, int n_in,
                              void* d_out, int out_size, void* d_ws, size_t ws_size,
                              hipStream_t stream) {
    const float* query = (const float*)d_in[0];
    const float* key   = (const float*)d_in[1];
    const float* value = (const float*)d_in[2];
    const float* qmask = (const float*)d_in[3];
    const float* kmask = (const float*)d_in[4];
    const float* Wq = (const float*)d_in[5];
    const float* bq = (const float*)d_in[6];
    const float* Wk = (const float*)d_in[7];
    const float* bk = (const float*)d_in[8];
    const float* Wv = (const float*)d_in[9];
    const float* bv = (const float*)d_in[10];
    const float* Wo = (const float*)d_in[11];
    const float* bo = (const float*)d_in[12];
    const float* Wf = (const float*)d_in[13];
    const float* bfin = (const float*)d_in[14];
    float* out = (float*)d_out;

    char* ws = (char*)d_ws;
    u16*   WT  = (u16*)  (ws + 0);          // 6291456
    u16*   W2T = (u16*)  (ws + 6291456);    // 2097152
    float* b2  = (float*)(ws + 8388608);    // 4096
    u16*   qbf = (u16*)  (ws + 8392704);    // 8388608
    u16*   kbf = (u16*)  (ws + 16781312);   // 8388608
    u16*   vbf = (u16*)  (ws + 25169920);   // 8388608
    u16*   att = (u16*)  (ws + 33558528);   // 8388608
    u16*   vtg = (u16*)  (ws + 41947136);   // 8388608
    float* kb  = (float*)(ws + 50335744);   // 16384  (end ~50.4 MB)

    hipMemsetAsync(b2, 0, 1024 * sizeof(float), stream);
    transpose_w_kernel<<<dim3(16, 16, 3), 256, 0, stream>>>(Wq, Wk, Wv, WT);
    build_w2t_kernel<<<dim3(16, 16), 256, 0, stream>>>(Wo, bo, Wf, bfin, W2T, b2);
    kbias_kernel<<<dim3(16), 256, 0, stream>>>(kmask, kb);
    gemm_qkv_kernel<<<dim3(8, 32, 3), 256, 0, stream>>>(query, key, value, WT, bq, bk, bv, qbf, kbf, vbf);
    transpose_v_kernel<<<dim3(32, 32), 256, 0, stream>>>(vbf, vtg);
    attn_kernel<<<dim3(1024), 256, 0, stream>>>(qbf, kbf, vtg, kb, qmask, att);
    gemm_final_kernel<<<dim3(8, 32), 256, 0, stream>>>(att, W2T, b2, out);
}

// Round 3
// 216.454 us; speedup vs baseline: 1.7250x; 1.7250x over previous
//
#include <hip/hip_runtime.h>

typedef unsigned short u16;
typedef unsigned int u32;
typedef __bf16 bf16x8 __attribute__((ext_vector_type(8)));
typedef float f32x4 __attribute__((ext_vector_type(4)));
typedef unsigned short u16x4 __attribute__((ext_vector_type(4)));
typedef unsigned short u16x8 __attribute__((ext_vector_type(8)));
typedef unsigned int u32x4 __attribute__((ext_vector_type(4)));

#define BB 2
#define SS 2048
#define EE 1024
#define HH 16
#define DD 64

static __device__ inline u16 f2bf(float f) {
    union { float f; unsigned int u; } v; v.f = f;
    unsigned int u = v.u;
    unsigned int r = (u + 0x7FFFu + ((u >> 16) & 1u)) >> 16;  // RNE
    return (u16)r;
}

static __device__ inline u32 cvt_pk_bf16(float lo, float hi) {
    u32 r;
    asm volatile("v_cvt_pk_bf16_f32 %0, %1, %2" : "=v"(r) : "v"(lo), "v"(hi));
    return r;
}

static __device__ __forceinline__ void gl_lds16(const u16* g, u16* l) {
    __builtin_amdgcn_global_load_lds(
        (const __attribute__((address_space(1))) void*)g,
        (__attribute__((address_space(3))) void*)l, 16, 0, 0);
}

// ---------------- K0a: transpose Wq/Wk/Wv [H,E,D] f32 -> WT [3*1024][1024] bf16 ----------------
__global__ __launch_bounds__(256) void transpose_w_kernel(
    const float* __restrict__ Wq, const float* __restrict__ Wk, const float* __restrict__ Wv,
    u16* __restrict__ WT)
{
    const int z = blockIdx.z;
    const int h = blockIdx.y;
    const int e0 = blockIdx.x * 64;
    const float* W = (z == 0) ? Wq : (z == 1) ? Wk : Wv;
    __shared__ float t_lds[64][68];
    const int tid = threadIdx.x;
#pragma unroll
    for (int it = 0; it < 4; ++it) {
        int s = tid + it * 256;
        int i = s >> 4, d4 = (s & 15) * 4;
        const float4 v = *reinterpret_cast<const float4*>(&W[((size_t)h * EE + e0 + i) * DD + d4]);
        t_lds[i][d4 + 0] = v.x; t_lds[i][d4 + 1] = v.y;
        t_lds[i][d4 + 2] = v.z; t_lds[i][d4 + 3] = v.w;
    }
    __syncthreads();
#pragma unroll
    for (int it = 0; it < 4; ++it) {
        int s = tid + it * 256;
        int d = s >> 4, i4 = (s & 15) * 4;
        u16x4 o;
        o[0] = f2bf(t_lds[i4 + 0][d]); o[1] = f2bf(t_lds[i4 + 1][d]);
        o[2] = f2bf(t_lds[i4 + 2][d]); o[3] = f2bf(t_lds[i4 + 3][d]);
        *reinterpret_cast<u16x4*>(&WT[((size_t)z * 1024 + h * 64 + d) * EE + e0 + i4]) = o;
    }
}

// ---------------- K0b: W2T[e][h*D+d] = sum_o Wo[h,d,o]*Wf[h*O+o,e]; b2 ----------------
__global__ __launch_bounds__(256) void build_w2t_kernel(
    const float* __restrict__ Wo, const float* __restrict__ bo,
    const float* __restrict__ Wf, const float* __restrict__ bfin,
    u16* __restrict__ W2T, float* __restrict__ b2)
{
    const int h = blockIdx.y;
    const int e0 = blockIdx.x * 64;
    __shared__ float wo_lds[64][65];  // [d][o]
    __shared__ float wf_lds[64][65];  // [o][i]
    const int tid = threadIdx.x;
#pragma unroll
    for (int it = 0; it < 4; ++it) {
        int s = tid + it * 256;
        int r = s >> 4, c4 = (s & 15) * 4;
        const float4 a = *reinterpret_cast<const float4*>(&Wo[((size_t)h * 64 + r) * 64 + c4]);
        wo_lds[r][c4 + 0] = a.x; wo_lds[r][c4 + 1] = a.y; wo_lds[r][c4 + 2] = a.z; wo_lds[r][c4 + 3] = a.w;
        const float4 b = *reinterpret_cast<const float4*>(&Wf[((size_t)(h * 64 + r)) * EE + e0 + c4]);
        wf_lds[r][c4 + 0] = b.x; wf_lds[r][c4 + 1] = b.y; wf_lds[r][c4 + 2] = b.z; wf_lds[r][c4 + 3] = b.w;
    }
    __syncthreads();
    const int d = tid & 63;
    const int i0 = (tid >> 6) * 16;
#pragma unroll
    for (int ii = 0; ii < 16; ++ii) {
        int i = i0 + ii;
        float acc = 0.f;
#pragma unroll 8
        for (int o = 0; o < 64; ++o) acc += wo_lds[d][o] * wf_lds[o][i];
        W2T[((size_t)(e0 + i)) * 1024 + h * 64 + d] = f2bf(acc);
    }
    if (tid < 64) {
        int i = tid;
        float acc = 0.f;
        for (int o = 0; o < 64; ++o) acc += bo[h * 64 + o] * wf_lds[o][i];
        if (h == 0) acc += bfin[e0 + i];
        atomicAdd(&b2[e0 + i], acc);
    }
}

// ---------------- K0c: kbias[b][t] = kmask ? 0 : -2e30 ----------------
__global__ __launch_bounds__(256) void kbias_kernel(const float* __restrict__ km, float* __restrict__ kb)
{
    int i = blockIdx.x * 256 + threadIdx.x;
    if (i < BB * SS) kb[i] = (km[i] != 0.f) ? 0.f : -2e30f;
}

// ---------------- K1: QKV projection GEMM ----------------
__global__ __launch_bounds__(256) void gemm_qkv_kernel(
    const float* __restrict__ query, const float* __restrict__ key, const float* __restrict__ value,
    const u16* __restrict__ WT,
    const float* __restrict__ bq, const float* __restrict__ bk, const float* __restrict__ bv,
    u16* __restrict__ qbf, u16* __restrict__ kbf, u16* __restrict__ vbf)
{
    const int z = blockIdx.z;
    const float* A   = (z == 0) ? query : (z == 1) ? key : value;
    const float* bia = (z == 0) ? bq    : (z == 1) ? bk  : bv;
    u16* outp        = (z == 0) ? qbf   : (z == 1) ? kbf : vbf;
    const u16* BT = WT + (size_t)z * 1024 * 1024;

    const int m0 = blockIdx.y * 128;
    const int n0 = blockIdx.x * 128;

    __shared__ u16 a_lds[128][72];
    __shared__ u16 b_lds[128][72];

    const int tid = threadIdx.x;
    const int lane = tid & 63;
    const int w = tid >> 6;
    const int wm = w >> 1, wn = w & 1;
    const int lrow = lane & 15;
    const int lgrp = lane >> 4;

    f32x4 acc[4][4] = {};

    for (int k0 = 0; k0 < 1024; k0 += 64) {
#pragma unroll
        for (int it = 0; it < 8; ++it) {
            int s = tid + it * 256;
            int row = s >> 4, c4 = (s & 15) * 4;
            const float4 v = *reinterpret_cast<const float4*>(&A[(size_t)(m0 + row) * 1024 + k0 + c4]);
            u16x4 o;
            o[0] = f2bf(v.x); o[1] = f2bf(v.y); o[2] = f2bf(v.z); o[3] = f2bf(v.w);
            *reinterpret_cast<u16x4*>(&a_lds[row][c4]) = o;
        }
#pragma unroll
        for (int it = 0; it < 4; ++it) {
            int s = tid + it * 256;
            int row = s >> 3, c8 = (s & 7) * 8;
            *reinterpret_cast<u16x8*>(&b_lds[row][c8]) =
                *reinterpret_cast<const u16x8*>(&BT[(size_t)(n0 + row) * 1024 + k0 + c8]);
        }
        __syncthreads();

#pragma unroll
        for (int kk = 0; kk < 2; ++kk) {
            bf16x8 af[4], bfr[4];
#pragma unroll
            for (int i = 0; i < 4; ++i)
                af[i] = *reinterpret_cast<const bf16x8*>(&a_lds[wm * 64 + i * 16 + lrow][kk * 32 + lgrp * 8]);
#pragma unroll
            for (int j = 0; j < 4; ++j)
                bfr[j] = *reinterpret_cast<const bf16x8*>(&b_lds[wn * 64 + j * 16 + lrow][kk * 32 + lgrp * 8]);
#pragma unroll
            for (int i = 0; i < 4; ++i)
#pragma unroll
                for (int j = 0; j < 4; ++j)
                    acc[i][j] = __builtin_amdgcn_mfma_f32_16x16x32_bf16(af[i], bfr[j], acc[i][j], 0, 0, 0);
        }
        __syncthreads();
    }

#pragma unroll
    for (int i = 0; i < 4; ++i) {
#pragma unroll
        for (int j = 0; j < 4; ++j) {
            int n = n0 + wn * 64 + j * 16 + lrow;
            int h = n >> 6, d = n & 63;
            float bb = bia[n];
#pragma unroll
            for (int r = 0; r < 4; ++r) {
                int m = m0 + wm * 64 + i * 16 + lgrp * 4 + r;
                int b = m >> 11, srow = m & 2047;
                outp[((size_t)(b * HH + h) * SS + srow) * DD + d] = f2bf(acc[i][j][r] + bb);
            }
        }
    }
}

// ---------------- K1b: transpose V [B,H,S,D] -> [B,H,D,S] (bf16) ----------------
__global__ __launch_bounds__(256) void transpose_v_kernel(
    const u16* __restrict__ vbf, u16* __restrict__ vtg)
{
    const int s0 = blockIdx.x * 64;
    const int bh = blockIdx.y;
    __shared__ u16 t_lds[64][72];
    const int tid = threadIdx.x;
#pragma unroll
    for (int rr = 0; rr < 2; ++rr) {
        int idx = tid + rr * 256;
        int row = idx >> 3, c8 = (idx & 7) * 8;
        *reinterpret_cast<u16x8*>(&t_lds[row][c8]) =
            *reinterpret_cast<const u16x8*>(&vbf[((size_t)bh * SS + s0 + row) * DD + c8]);
    }
    __syncthreads();
#pragma unroll
    for (int rr = 0; rr < 2; ++rr) {
        int idx = tid + rr * 256;
        int d = idx >> 3, tt = (idx & 7) * 8;
        u16x8 o;
#pragma unroll
        for (int j = 0; j < 8; ++j) o[j] = t_lds[tt + j][d];
        *reinterpret_cast<u16x8*>(&vtg[((size_t)bh * DD + d) * SS + s0 + tt]) = o;
    }
}

// ---------------- K2: flash attention — swapped QK^T in-reg softmax + 2-phase LDS pipeline ----------------
__global__ __launch_bounds__(256) void attn_kernel(
    const u16* __restrict__ qbf, const u16* __restrict__ kbf, const u16* __restrict__ vtg,
    const float* __restrict__ kbias, const float* __restrict__ qmask,
    u16* __restrict__ att)
{
    // XCD-aware swizzle: same-XCD neighbors share (b,h) so K/V tiles are L2-resident
    const int id = blockIdx.x;
    const int bh = (id & 7) * 4 + ((id >> 3) & 3);
    const int qt = id >> 5;
    const int b = bh >> 4, h = bh & 15;

    const int tid = threadIdx.x;
    const int w = tid >> 6;
    const int lane = tid & 63;
    const int lrow = lane & 15, lgrp = lane >> 4;
    const int q0 = qt * 64 + w * 16;

    __shared__ u16 k_lds[2][64][64];  // [buf][t][d], XOR-swizzled content
    __shared__ u16 v_lds[2][64][64];  // [buf][d][t], XOR-swizzled content

    const size_t bhoff = (size_t)bh * SS * DD;
    const u16* Kb = kbf + bhoff;                    // [2048][64]
    const u16* Vb = vtg + (size_t)bh * DD * SS;     // [64][2048]
    const float* kbb = kbias + (size_t)b * SS;

    // Q as MFMA B-operand: col=q=lane&15, k=d
    bf16x8 aq[2];
#pragma unroll
    for (int kk = 0; kk < 2; ++kk)
        aq[kk] = *reinterpret_cast<const bf16x8*>(&qbf[bhoff + (size_t)(q0 + lrow) * DD + kk * 32 + lgrp * 8]);

    f32x4 acc[4] = {};   // O[q'=lgrp*4+r][d=nf*16+lrow]
    float m_run = -1e30f, l_run = 0.f;
    const float sscale = 0.125f * 1.44269504089f;  // 1/sqrt(64) * log2(e)

    // stage one 64-row K tile + 64-row V^T tile into buf via global_load_lds.
    // LDS dest is linear (slot s*16B); global SOURCE is pre-swizzled so that a
    // ds_read at byte (row*128 + (col ^ ((row&7)<<4))) returns logical (row,col).
    const int s0i = tid, s1i = tid + 256;
    const int r0 = s0i >> 3, lc0 = ((s0i & 7) * 16) ^ ((r0 & 7) << 4);
    const int r1 = s1i >> 3, lc1 = ((s1i & 7) * 16) ^ ((r1 & 7) << 4);

#define STAGE(bufi, t0s)                                                              \
    do {                                                                              \
        u16* kb_ = &k_lds[bufi][0][0];                                                \
        u16* vb_ = &v_lds[bufi][0][0];                                                \
        gl_lds16(Kb + (size_t)((t0s) + r0) * 64 + (lc0 >> 1), kb_ + s0i * 8);         \
        gl_lds16(Vb + (size_t)r0 * SS + (t0s) + (lc0 >> 1),  vb_ + s0i * 8);          \
        gl_lds16(Kb + (size_t)((t0s) + r1) * 64 + (lc1 >> 1), kb_ + s1i * 8);         \
        gl_lds16(Vb + (size_t)r1 * SS + (t0s) + (lc1 >> 1),  vb_ + s1i * 8);          \
    } while (0)

    STAGE(0, 0);
    asm volatile("s_waitcnt vmcnt(0)" ::: "memory");
    __syncthreads();

    int cur = 0;
    for (int ti = 0; ti < 32; ++ti) {
        const int t0 = ti * 64;
        // prefetch next tile into the other buffer (hidden under this tile's compute)
        const int tn = (ti < 31) ? t0 + 64 : t0;
        STAGE(cur ^ 1, tn);

        // kbias for this tile (broadcast loads, in flight during QK^T)
        float4 kb4[4];
#pragma unroll
        for (int nt = 0; nt < 4; ++nt)
            kb4[nt] = *reinterpret_cast<const float4*>(kbb + t0 + nt * 16 + lgrp * 4);

        // swapped QK^T: C[t][q]; lane holds q=lane&15, t = nt*16 + lgrp*4 + reg
        const char* kbase = reinterpret_cast<const char*>(&k_lds[cur][0][0]);
        f32x4 sc4[4];
#pragma unroll
        for (int nt = 0; nt < 4; ++nt) {
            int row = nt * 16 + lrow;
            int swz = (row & 7) << 4;
            bf16x8 k0 = *reinterpret_cast<const bf16x8*>(kbase + row * 128 + ((lgrp * 16) ^ swz));
            bf16x8 k1 = *reinterpret_cast<const bf16x8*>(kbase + row * 128 + ((64 + lgrp * 16) ^ swz));
            f32x4 s = {};
            s = __builtin_amdgcn_mfma_f32_16x16x32_bf16(k0, aq[0], s, 0, 0, 0);
            s = __builtin_amdgcn_mfma_f32_16x16x32_bf16(k1, aq[1], s, 0, 0, 0);
            sc4[nt] = s;
        }

        // scale + additive mask bias (log2 domain)
        float p[4][4];
        float vmax = -3.0e38f;
#pragma unroll
        for (int nt = 0; nt < 4; ++nt) {
            float kbv[4] = { kb4[nt].x, kb4[nt].y, kb4[nt].z, kb4[nt].w };
#pragma unroll
            for (int r = 0; r < 4; ++r) {
                float x = sc4[nt][r] * sscale + kbv[r];
                p[nt][r] = x;
                vmax = fmaxf(vmax, x);
            }
        }
        vmax = fmaxf(vmax, __shfl_xor(vmax, 16));
        vmax = fmaxf(vmax, __shfl_xor(vmax, 32));

        // defer-max (T13)
        if (!__all((vmax - m_run) <= 8.0f)) {
            float mnew = fmaxf(m_run, vmax);
            float alpha = exp2f(m_run - mnew);
            m_run = mnew;
            l_run *= alpha;
#pragma unroll
            for (int r = 0; r < 4; ++r) {
                float ar = __shfl(alpha, lgrp * 4 + r);
#pragma unroll
                for (int nf = 0; nf < 4; ++nf) acc[nf][r] *= ar;
            }
        }

        float psum = 0.f;
#pragma unroll
        for (int nt = 0; nt < 4; ++nt)
#pragma unroll
            for (int r = 0; r < 4; ++r) {
                float e = exp2f(p[nt][r] - m_run);
                p[nt][r] = e;
                psum += e;
            }
        l_run += psum;

        // pack P to bf16 pairs
        u32 hh[4][2];
#pragma unroll
        for (int nt = 0; nt < 4; ++nt) {
            hh[nt][0] = cvt_pk_bf16(p[nt][0], p[nt][1]);
            hh[nt][1] = cvt_pk_bf16(p[nt][2], p[nt][3]);
        }

        // exchange into PV A-frag layout: lane needs t = kk2*32 + lgrp*8 + j
        const int src_lo = lrow + ((lgrp & 1) << 5);
        const int src_hi = src_lo + 16;
        const bool hiSel = (lgrp >> 1) & 1;
        const char* vbase = reinterpret_cast<const char*>(&v_lds[cur][0][0]);
#pragma unroll
        for (int kk2 = 0; kk2 < 2; ++kk2) {
            u32 w0l = __shfl(hh[2 * kk2][0], src_lo);
            u32 w0h = __shfl(hh[2 * kk2 + 1][0], src_lo);
            u32 w1l = __shfl(hh[2 * kk2][1], src_lo);
            u32 w1h = __shfl(hh[2 * kk2 + 1][1], src_lo);
            u32 w2l = __shfl(hh[2 * kk2][0], src_hi);
            u32 w2h = __shfl(hh[2 * kk2 + 1][0], src_hi);
            u32 w3l = __shfl(hh[2 * kk2][1], src_hi);
            u32 w3h = __shfl(hh[2 * kk2 + 1][1], src_hi);
            u32x4 a4;
            a4[0] = hiSel ? w0h : w0l;
            a4[1] = hiSel ? w1h : w1l;
            a4[2] = hiSel ? w2h : w2l;
            a4[3] = hiSel ? w3h : w3l;
            bf16x8 pa = __builtin_bit_cast(bf16x8, a4);
#pragma unroll
            for (int nf = 0; nf < 4; ++nf) {
                int row = nf * 16 + lrow;
                int swz = (row & 7) << 4;
                bf16x8 bv8 = *reinterpret_cast<const bf16x8*>(vbase + row * 128 + ((kk2 * 64 + lgrp * 16) ^ swz));
                acc[nf] = __builtin_amdgcn_mfma_f32_16x16x32_bf16(pa, bv8, acc[nf], 0, 0, 0);
            }
        }

        asm volatile("s_waitcnt vmcnt(0)" ::: "memory");
        __syncthreads();
        cur ^= 1;
    }
#undef STAGE

    // epilogue: combine l across the 4 lane-groups, normalize, store
    float l1 = l_run + __shfl_xor(l_run, 16);
    l1 += __shfl_xor(l1, 32);
#pragma unroll
    for (int r = 0; r < 4; ++r) {
        int qq = lgrp * 4 + r;
        float lq = __shfl(l1, qq);
        float qm = qmask[(size_t)b * SS + q0 + qq];
        float inv = (lq > 0.f && qm != 0.f) ? 1.f / lq : 0.f;
#pragma unroll
        for (int nf = 0; nf < 4; ++nf)
            att[((size_t)b * SS + q0 + qq) * 1024 + h * 64 + nf * 16 + lrow] = f2bf(acc[nf][r] * inv);
    }
}

// ---------------- K3: final GEMM: att[4096,1024] bf16 x W2T -> out f32 + b2 ----------------
__global__ __launch_bounds__(256) void gemm_final_kernel(
    const u16* __restrict__ A, const u16* __restrict__ BT,
    const float* __restrict__ b2, float* __restrict__ out)
{
    const int m0 = blockIdx.y * 128;
    const int n0 = blockIdx.x * 128;

    __shared__ u16 a_lds[128][72];
    __shared__ u16 b_lds[128][72];

    const int tid = threadIdx.x;
    const int lane = tid & 63;
    const int w = tid >> 6;
    const int wm = w >> 1, wn = w & 1;
    const int lrow = lane & 15;
    const int lgrp = lane >> 4;

    f32x4 acc[4][4] = {};

    for (int k0 = 0; k0 < 1024; k0 += 64) {
#pragma unroll
        for (int it = 0; it < 4; ++it) {
            int s = tid + it * 256;
            int row = s >> 3, c8 = (s & 7) * 8;
            *reinterpret_cast<u16x8*>(&a_lds[row][c8]) =
                *reinterpret_cast<const u16x8*>(&A[(size_t)(m0 + row) * 1024 + k0 + c8]);
        }
#pragma unroll
        for (int it = 0; it < 4; ++it) {
            int s = tid + it * 256;
            int row = s >> 3, c8 = (s & 7) * 8;
            *reinterpret_cast<u16x8*>(&b_lds[row][c8]) =
                *reinterpret_cast<const u16x8*>(&BT[(size_t)(n0 + row) * 1024 + k0 + c8]);
        }
        __syncthreads();

#pragma unroll
        for (int kk = 0; kk < 2; ++kk) {
            bf16x8 af[4], bfr[4];
#pragma unroll
            for (int i = 0; i < 4; ++i)
                af[i] = *reinterpret_cast<const bf16x8*>(&a_lds[wm * 64 + i * 16 + lrow][kk * 32 + lgrp * 8]);
#pragma unroll
            for (int j = 0; j < 4; ++j)
                bfr[j] = *reinterpret_cast<const bf16x8*>(&b_lds[wn * 64 + j * 16 + lrow][kk * 32 + lgrp * 8]);
#pragma unroll
            for (int i = 0; i < 4; ++i)
#pragma unroll
                for (int j = 0; j < 4; ++j)
                    acc[i][j] = __builtin_amdgcn_mfma_f32_16x16x32_bf16(af[i], bfr[j], acc[i][j], 0, 0, 0);
        }
        __syncthreads();
    }

#pragma unroll
    for (int i = 0; i < 4; ++i) {
#pragma unroll
        for (int j = 0; j < 4; ++j) {
            int n = n0 + wn * 64 + j * 16 + lrow;
            float bb = b2[n];
#pragma unroll
            for (int r = 0; r < 4; ++r) {
                int m = m0 + wm * 64 + i * 16 + lgrp * 4 + r;
                out[(size_t)m * 1024 + n] = acc[i][j][r] + bb;
            }
        }
    }
}

extern "C" void kernel_launch(void* const* d_in, const int* in_sizes, int n_in,
                              void* d_out, int out_size, void* d_ws, size_t ws_size,
                              hipStream_t stream) {
    const float* query = (const float*)d_in[0];
    const float* key   = (const float*)d_in[1];
    const float* value = (const float*)d_in[2];
    const float* qmask = (const float*)d_in[3];
    const float* kmask = (const float*)d_in[4];
    const float* Wq = (const float*)d_in[5];
    const float* bq = (const float*)d_in[6];
    const float* Wk = (const float*)d_in[7];
    const float* bk = (const float*)d_in[8];
    const float* Wv = (const float*)d_in[9];
    const float* bv = (const float*)d_in[10];
    const float* Wo = (const float*)d_in[11];
    const float* bo = (const float*)d_in[12];
    const float* Wf = (const float*)d_in[13];
    const float* bfin = (const float*)d_in[14];
    float* out = (float*)d_out;

    char* ws = (char*)d_ws;
    u16*   WT  = (u16*)  (ws + 0);          // 6291456
    u16*   W2T = (u16*)  (ws + 6291456);    // 2097152
    float* b2  = (float*)(ws + 8388608);    // 4096
    u16*   qbf = (u16*)  (ws + 8392704);    // 8388608
    u16*   kbf = (u16*)  (ws + 16781312);   // 8388608
    u16*   vbf = (u16*)  (ws + 25169920);   // 8388608
    u16*   att = (u16*)  (ws + 33558528);   // 8388608
    u16*   vtg = (u16*)  (ws + 41947136);   // 8388608
    float* kb  = (float*)(ws + 50335744);   // 16384  (end ~50.4 MB)

    hipMemsetAsync(b2, 0, 1024 * sizeof(float), stream);
    transpose_w_kernel<<<dim3(16, 16, 3), 256, 0, stream>>>(Wq, Wk, Wv, WT);
    build_w2t_kernel<<<dim3(16, 16), 256, 0, stream>>>(Wo, bo, Wf, bfin, W2T, b2);
    kbias_kernel<<<dim3(16), 256, 0, stream>>>(kmask, kb);
    gemm_qkv_kernel<<<dim3(8, 32, 3), 256, 0, stream>>>(query, key, value, WT, bq, bk, bv, qbf, kbf, vbf);
    transpose_v_kernel<<<dim3(32, 32), 256, 0, stream>>>(vbf, vtg);
    attn_kernel<<<dim3(1024), 256, 0, stream>>>(qbf, kbf, vtg, kb, qmask, att);
    gemm_final_kernel<<<dim3(8, 32), 256, 0, stream>>>(att, W2T, b2, out);
}